// Round 2
// baseline (710.104 us; speedup 1.0000x reference)
//
#include <hip/hip_runtime.h>
#include <stdint.h>

// Problem constants
#define BB    8
#define NN_   16384
#define SS    1024
#define PP    131072    // BB*NN_
#define CIN   512
#define CMID  256
#define COUT  256

typedef short  bf16x8 __attribute__((ext_vector_type(8)));
typedef float  f32x4  __attribute__((ext_vector_type(4)));
typedef unsigned short u16x8 __attribute__((ext_vector_type(8)));

__device__ __forceinline__ float bf2f(unsigned short u){
  union { unsigned int i; float f; } v; v.i = ((unsigned int)u) << 16; return v.f;
}
__device__ __forceinline__ unsigned short f2bf(float f){
  union { float f; unsigned int i; } v; v.f = f;
  unsigned int r = (v.i + 0x7fffu + ((v.i >> 16) & 1u)) >> 16;  // RNE
  return (unsigned short)r;
}

// async global->LDS, 16B per lane; LDS dest must be wave-uniform base (+lane*16 implicit)
__device__ __forceinline__ void async_ld16(const void* g, void* l){
  const uint32_t __attribute__((address_space(1)))* gp =
    reinterpret_cast<const uint32_t __attribute__((address_space(1)))*>(reinterpret_cast<uintptr_t>(g));
  uint32_t __attribute__((address_space(3)))* lp =
    reinterpret_cast<uint32_t __attribute__((address_space(3)))*>(reinterpret_cast<uintptr_t>(l));
  __builtin_amdgcn_global_load_lds(gp, lp, 16, 0, 0);
}

// ---------------------------------------------------------------------------
// Prep: weights fp32->bf16, zero BN stats. (conv biases b0/b1 cancel exactly in
// training-mode BN: (y+b) - mean(y+b) == y - mean(y); variance unchanged.)
__global__ void k_prep(const float* __restrict__ w0, const float* __restrict__ w1,
                       unsigned short* __restrict__ w0b, unsigned short* __restrict__ w1b,
                       float* __restrict__ bn)
{
  int idx = blockIdx.x * 256 + threadIdx.x;   // grid 512 -> 131072 threads
  if (idx < 131072) w0b[idx] = f2bf(w0[idx]);
  if (idx < 65536)  w1b[idx] = f2bf(w1[idx]);
  if (idx < 2048)   bn[idx]  = 0.0f;          // stats + params region
}

// ---------------------------------------------------------------------------
// points2 [B][256][S] fp32 -> p2t [B][S][256] fp32 (coalesced gather rows)
__global__ void k_p2t(const float* __restrict__ p2, float* __restrict__ p2t)
{
  __shared__ float t[32][33];
  const int b = blockIdx.z, c0 = blockIdx.y * 32, s0 = blockIdx.x * 32;
  const int tx = threadIdx.x, ty = threadIdx.y;   // (32,8)
#pragma unroll
  for (int r = 0; r < 4; r++)
    t[ty + r*8][tx] = p2[((size_t)b*256 + c0 + ty + r*8) * SS + s0 + tx];
  __syncthreads();
#pragma unroll
  for (int r = 0; r < 4; r++)
    p2t[((size_t)b*SS + s0 + ty + r*8) * 256 + c0 + tx] = t[tx][ty + r*8];
}

// points1 [B][256][N] fp32 -> xcat[p][0:256] bf16  (row stride 512)
__global__ void k_p1t(const float* __restrict__ p1, unsigned short* __restrict__ xcat)
{
  __shared__ float t[32][33];
  const int b = blockIdx.z, c0 = blockIdx.y * 32, n0 = blockIdx.x * 32;
  const int tx = threadIdx.x, ty = threadIdx.y;
#pragma unroll
  for (int r = 0; r < 4; r++)
    t[ty + r*8][tx] = p1[((size_t)b*256 + c0 + ty + r*8) * (size_t)NN_ + n0 + tx];
  __syncthreads();
#pragma unroll
  for (int r = 0; r < 4; r++)
    xcat[((size_t)b*NN_ + n0 + ty + r*8) * 512 + c0 + tx] = f2bf(t[tx][ty + r*8]);
}

// ---------------------------------------------------------------------------
// 3-NN + inverse-distance interp -> xcat[p][256:512] bf16
// fp64 direct-difference distances: the expanded fp32 formula (qq+pp-2qp) has
// ~1e-5 abs cancellation noise near d~0.02, which flips 3rd/4th-NN selection
// vs the fp64 numpy reference for ~100 of 131072 points -> absmax ~1 (R1 bug).
__global__ __launch_bounds__(256) void k_nn(const float* __restrict__ xyz1,
                                            const float* __restrict__ xyz2,
                                            const float* __restrict__ p2t,
                                            unsigned short* __restrict__ xcat)
{
  __shared__ double4 pts[SS];         // 32 KB, wave-uniform (broadcast) reads
  __shared__ int   ids[256][3];
  __shared__ float wts[256][3];
  const int b = blockIdx.y, n0 = blockIdx.x * 256, tid = threadIdx.x;

  for (int s = tid; s < SS; s += 256) {
    double x = (double)xyz2[((size_t)b*3 + 0) * SS + s];
    double y = (double)xyz2[((size_t)b*3 + 1) * SS + s];
    double z = (double)xyz2[((size_t)b*3 + 2) * SS + s];
    pts[s] = make_double4(x, y, z, 0.0);
  }
  __syncthreads();

  const int n = n0 + tid;
  const double qx = (double)xyz1[((size_t)b*3 + 0) * NN_ + n];
  const double qy = (double)xyz1[((size_t)b*3 + 1) * NN_ + n];
  const double qz = (double)xyz1[((size_t)b*3 + 2) * NN_ + n];

  double d0 = 1e300, d1 = 1e300, d2 = 1e300;
  int   i0 = 0, i1 = 0, i2 = 0;
  for (int s = 0; s < SS; s++) {
    double4 p = pts[s];
    double dx = qx - p.x, dy = qy - p.y, dz = qz - p.z;
    double d = dx*dx + dy*dy + dz*dz;
    if (d < d2) {
      if (d < d1) {
        d2 = d1; i2 = i1;
        if (d < d0) { d1 = d0; i1 = i0; d0 = d; i0 = s; }
        else        { d1 = d;  i1 = s; }
      } else { d2 = d; i2 = s; }
    }
  }
  double r0 = 1.0/(d0 + 1e-8), r1 = 1.0/(d1 + 1e-8), r2 = 1.0/(d2 + 1e-8);
  double rs = 1.0/(r0 + r1 + r2);
  ids[tid][0] = i0; ids[tid][1] = i1; ids[tid][2] = i2;
  wts[tid][0] = (float)(r0*rs); wts[tid][1] = (float)(r1*rs); wts[tid][2] = (float)(r2*rs);
  __syncthreads();

  // cooperative gather: per point j, 256 threads cover 256 channels (coalesced rows)
  for (int j = 0; j < 256; j++) {
    const float* ra = p2t + ((size_t)b*SS + ids[j][0]) * 256;
    const float* rb = p2t + ((size_t)b*SS + ids[j][1]) * 256;
    const float* rc = p2t + ((size_t)b*SS + ids[j][2]) * 256;
    float f = wts[j][0]*ra[tid] + wts[j][1]*rb[tid] + wts[j][2]*rc[tid];
    xcat[((size_t)b*NN_ + n0 + j) * 512 + 256 + tid] = f2bf(f);
  }
}

// ---------------------------------------------------------------------------
// NT GEMM: Y[p][o] = sum_c X[p][c]*W[o][c].  X:[P][K] bf16, W:[256][K] bf16.
// 128x128 tile, BK=32, 4 waves (2p x 2o), MFMA 16x16x32 bf16.
// Epilogue: per-channel sum/sumsq atomics (BN stats) + bf16 store.
__global__ __launch_bounds__(256) void k_gemm(const unsigned short* __restrict__ X,
                                              const unsigned short* __restrict__ W,
                                              unsigned short* __restrict__ Y,
                                              float* __restrict__ bnsum,
                                              float* __restrict__ bnsumsq,
                                              int K)
{
  __shared__ unsigned short Xs[128*32];   // 8 KB, [p][c] rows of 64B (granule=16B)
  __shared__ unsigned short Ws[128*32];
  const int tid  = threadIdx.x;
  const int wid  = tid >> 6, lane = tid & 63;
  const int quad = lane >> 4, l16 = lane & 15;
  const int wave_p = wid & 1, wave_o = wid >> 1;
  const size_t p0 = (size_t)blockIdx.x * 128;
  const int o0 = blockIdx.y * 128;

  f32x4 acc[4][4] = {};

  // staging granule -> (row, c8): row = g>>2, coff = (g&3)*8
  const int g2 = tid + 256;
  const int r1 = tid >> 2, c1 = (tid & 3) * 8;
  const int r2 = g2 >> 2,  c2 = (g2 & 3) * 8;
  unsigned short* ldsX1 = Xs + wid*512;        unsigned short* ldsX2 = Xs + 2048 + wid*512;
  unsigned short* ldsW1 = Ws + wid*512;        unsigned short* ldsW2 = Ws + 2048 + wid*512;
  const unsigned short* gX1 = X + (p0 + r1) * (size_t)K + c1;
  const unsigned short* gX2 = X + (p0 + r2) * (size_t)K + c2;
  const unsigned short* gW1 = W + (size_t)(o0 + r1) * K + c1;
  const unsigned short* gW2 = W + (size_t)(o0 + r2) * K + c2;

  for (int kk = 0; kk < K; kk += 32) {
    async_ld16(gX1 + kk, ldsX1);
    async_ld16(gX2 + kk, ldsX2);
    async_ld16(gW1 + kk, ldsW1);
    async_ld16(gW2 + kk, ldsW2);
    __syncthreads();   // waits vmcnt(0) for the LDS-direct loads
    bf16x8 af[4], bfr[4];
    const bf16x8* xv = (const bf16x8*)Xs;
    const bf16x8* wv = (const bf16x8*)Ws;
#pragma unroll
    for (int i = 0; i < 4; i++) {
      af[i]  = xv[(wave_p*64 + i*16 + l16) * 4 + quad];  // A[m=l16][k=quad*8+j]
      bfr[i] = wv[(wave_o*64 + i*16 + l16) * 4 + quad];  // B[n=l16][k=quad*8+j]
    }
#pragma unroll
    for (int pi = 0; pi < 4; pi++)
#pragma unroll
      for (int oi = 0; oi < 4; oi++)
        acc[pi][oi] = __builtin_amdgcn_mfma_f32_16x16x32_bf16(af[pi], bfr[oi], acc[pi][oi], 0, 0, 0);
    __syncthreads();
  }

  // BN stats: reduce over p (lane's 16 rows, then across quads), atomics per o
#pragma unroll
  for (int oi = 0; oi < 4; oi++) {
    float s = 0.0f, ss = 0.0f;
#pragma unroll
    for (int pi = 0; pi < 4; pi++)
#pragma unroll
      for (int i = 0; i < 4; i++) { float v = acc[pi][oi][i]; s += v; ss += v*v; }
    s  += __shfl_xor(s, 16, 64);  s  += __shfl_xor(s, 32, 64);
    ss += __shfl_xor(ss, 16, 64); ss += __shfl_xor(ss, 32, 64);
    if (quad == 0) {
      int o = o0 + wave_o*64 + oi*16 + l16;
      atomicAdd(&bnsum[o], s);
      atomicAdd(&bnsumsq[o], ss);
    }
  }
  // store raw y (bf16). D: row(p)=quad*4+i, col(o)=l16
#pragma unroll
  for (int pi = 0; pi < 4; pi++)
#pragma unroll
    for (int oi = 0; oi < 4; oi++)
#pragma unroll
      for (int i = 0; i < 4; i++) {
        size_t p = p0 + wave_p*64 + pi*16 + quad*4 + i;
        int    o = o0 + wave_o*64 + oi*16 + l16;
        Y[p * 256 + o] = f2bf(acc[pi][oi][i]);
      }
}

// ---------------------------------------------------------------------------
// BN param: scale = g*rsqrt(var+eps), shift = be - mean*scale
__global__ void k_bn(const float* __restrict__ sum, const float* __restrict__ sumsq,
                     const float* __restrict__ g, const float* __restrict__ be,
                     float* __restrict__ scale, float* __restrict__ shift)
{
  int o = threadIdx.x;
  const float inv = 1.0f / 131072.0f;
  float m  = sum[o] * inv;
  float v  = sumsq[o] * inv - m * m;
  float sc = g[o] * rsqrtf(v + 1e-5f);
  scale[o] = sc;
  shift[o] = be[o] - m * sc;
}

// elementwise z = relu(y*scale + shift), bf16 -> bf16 (keeps GEMM2 stage-able via lds-direct)
__global__ __launch_bounds__(256) void k_z(const unsigned short* __restrict__ y,
                                           const float* __restrict__ scale,
                                           const float* __restrict__ shift,
                                           unsigned short* __restrict__ z)
{
  size_t idx = ((size_t)blockIdx.x * 256 + threadIdx.x) * 8;
  int o = (int)(idx & 255);
  u16x8 v = *(const u16x8*)(y + idx);
  u16x8 r;
#pragma unroll
  for (int i = 0; i < 8; i++) {
    float f = bf2f(v[i]);
    float t = f * scale[o + i] + shift[o + i];
    r[i] = f2bf(fmaxf(t, 0.0f));
  }
  *(u16x8*)(z + idx) = r;
}

// final: y1[p][o] bf16 -> out[b][o][n] fp32 with BN+relu, LDS transpose
__global__ __launch_bounds__(256) void k_out(const unsigned short* __restrict__ y1,
                                             const float* __restrict__ scale,
                                             const float* __restrict__ shift,
                                             float* __restrict__ out)
{
  __shared__ float t[64][65];
  const int b = blockIdx.z, o0 = blockIdx.y * 64, n0 = blockIdx.x * 64;
  const int tx = threadIdx.x & 15, ty = threadIdx.x >> 4;
  const float4 sc = *(const float4*)(scale + o0 + tx*4);
  const float4 sh = *(const float4*)(shift + o0 + tx*4);
#pragma unroll
  for (int r = 0; r < 4; r++) {
    int nl = ty + r*16;
    const unsigned short* src = y1 + ((size_t)b*NN_ + n0 + nl) * 256 + o0 + tx*4;
    ushort4 v = *(const ushort4*)src;
    t[tx*4+0][nl] = fmaxf(bf2f(v.x) * sc.x + sh.x, 0.0f);
    t[tx*4+1][nl] = fmaxf(bf2f(v.y) * sc.y + sh.y, 0.0f);
    t[tx*4+2][nl] = fmaxf(bf2f(v.z) * sc.z + sh.z, 0.0f);
    t[tx*4+3][nl] = fmaxf(bf2f(v.w) * sc.w + sh.w, 0.0f);
  }
  __syncthreads();
#pragma unroll
  for (int r = 0; r < 4; r++) {
    int ol = ty + r*16;
    float4 o4 = make_float4(t[ol][tx*4+0], t[ol][tx*4+1], t[ol][tx*4+2], t[ol][tx*4+3]);
    *(float4*)(out + ((size_t)b*256 + o0 + ol) * (size_t)NN_ + n0 + tx*4) = o4;
  }
}

// ---------------------------------------------------------------------------
extern "C" void kernel_launch(void* const* d_in, const int* in_sizes, int n_in,
                              void* d_out, int out_size, void* d_ws, size_t ws_size,
                              hipStream_t stream)
{
  const float* xyz1 = (const float*)d_in[0];
  const float* xyz2 = (const float*)d_in[1];
  const float* p1   = (const float*)d_in[2];
  const float* p2   = (const float*)d_in[3];
  const float* w0   = (const float*)d_in[4];
  const float* g0   = (const float*)d_in[6];
  const float* be0  = (const float*)d_in[7];
  const float* w1   = (const float*)d_in[8];
  const float* g1   = (const float*)d_in[10];
  const float* be1  = (const float*)d_in[11];

  // workspace layout (~192.5 MiB):
  //   [0,128Mi)    xcat [P][512] bf16      (later reused: z=[0,64Mi), y1=[64Mi,128Mi))
  //   [128,192Mi)  y0 [P][256] bf16        (p2t aliases its first 8 MiB; dead before gemm1 writes)
  //   [192Mi,...]  w0b, w1b, bn stats/params
  char* ws = (char*)d_ws;
  unsigned short* xcat = (unsigned short*)(ws);
  unsigned short* y0   = (unsigned short*)(ws + 134217728ull);
  unsigned short* zbuf = (unsigned short*)(ws);
  unsigned short* y1   = (unsigned short*)(ws + 67108864ull);
  float*          p2t  = (float*)        (ws + 134217728ull);
  unsigned short* w0b  = (unsigned short*)(ws + 201326592ull);
  unsigned short* w1b  = (unsigned short*)(ws + 201588736ull);
  float*          bn   = (float*)        (ws + 201719808ull);
  // bn: [0]sum0 [256]sumsq0 [512]sum1 [768]sumsq1 [1024]scale0 [1280]shift0 [1536]scale1 [1792]shift1

  k_prep<<<512, 256, 0, stream>>>(w0, w1, w0b, w1b, bn);
  k_p2t <<<dim3(32, 8, 8),  dim3(32, 8), 0, stream>>>(p2, p2t);
  k_p1t <<<dim3(512, 8, 8), dim3(32, 8), 0, stream>>>(p1, xcat);
  k_nn  <<<dim3(64, 8), 256, 0, stream>>>(xyz1, xyz2, p2t, xcat);
  k_gemm<<<dim3(1024, 2), 256, 0, stream>>>(xcat, w0b, y0, bn + 0,   bn + 256, 512);
  k_bn  <<<1, 256, 0, stream>>>(bn + 0,   bn + 256, g0, be0, bn + 1024, bn + 1280);
  k_z   <<<16384, 256, 0, stream>>>(y0, bn + 1024, bn + 1280, zbuf);
  k_gemm<<<dim3(1024, 2), 256, 0, stream>>>(zbuf, w1b, y1, bn + 512, bn + 768, 256);
  k_bn  <<<1, 256, 0, stream>>>(bn + 512, bn + 768, g1, be1, bn + 1536, bn + 1792);
  k_out <<<dim3(256, 4, 8), 256, 0, stream>>>(y1, bn + 1536, bn + 1792, (float*)d_out);
}

// Round 3
// 678.655 us; speedup vs baseline: 1.0463x; 1.0463x over previous
//
#include <hip/hip_runtime.h>
#include <stdint.h>

// Problem constants
#define BB    8
#define NN_   16384
#define SS    1024
#define PP    131072    // BB*NN_
#define CIN   512
#define CMID  256
#define COUT  256

typedef short  bf16x8 __attribute__((ext_vector_type(8)));
typedef float  f32x4  __attribute__((ext_vector_type(4)));
typedef unsigned short u16x8 __attribute__((ext_vector_type(8)));

__device__ __forceinline__ float bf2f(unsigned short u){
  union { unsigned int i; float f; } v; v.i = ((unsigned int)u) << 16; return v.f;
}
__device__ __forceinline__ unsigned short f2bf(float f){
  union { float f; unsigned int i; } v; v.f = f;
  unsigned int r = (v.i + 0x7fffu + ((v.i >> 16) & 1u)) >> 16;  // RNE
  return (unsigned short)r;
}

// async global->LDS, 16B per lane; LDS dest must be wave-uniform base (+lane*16 implicit)
__device__ __forceinline__ void async_ld16(const void* g, void* l){
  const uint32_t __attribute__((address_space(1)))* gp =
    reinterpret_cast<const uint32_t __attribute__((address_space(1)))*>(reinterpret_cast<uintptr_t>(g));
  uint32_t __attribute__((address_space(3)))* lp =
    reinterpret_cast<uint32_t __attribute__((address_space(3)))*>(reinterpret_cast<uintptr_t>(l));
  __builtin_amdgcn_global_load_lds(gp, lp, 16, 0, 0);
}

// ---------------------------------------------------------------------------
// Prep: weights fp32->bf16, zero BN stats. (conv biases b0/b1 cancel exactly in
// training-mode BN: (y+b) - mean(y+b) == y - mean(y); variance unchanged.)
__global__ void k_prep(const float* __restrict__ w0, const float* __restrict__ w1,
                       unsigned short* __restrict__ w0b, unsigned short* __restrict__ w1b,
                       float* __restrict__ bn)
{
  int idx = blockIdx.x * 256 + threadIdx.x;   // grid 512 -> 131072 threads
  if (idx < 131072) w0b[idx] = f2bf(w0[idx]);
  if (idx < 65536)  w1b[idx] = f2bf(w1[idx]);
  if (idx < 2048)   bn[idx]  = 0.0f;          // stats + params region
}

// ---------------------------------------------------------------------------
// points2 [B][256][S] fp32 -> p2t [B][S][256] fp32 (coalesced gather rows)
__global__ void k_p2t(const float* __restrict__ p2, float* __restrict__ p2t)
{
  __shared__ float t[32][33];
  const int b = blockIdx.z, c0 = blockIdx.y * 32, s0 = blockIdx.x * 32;
  const int tx = threadIdx.x, ty = threadIdx.y;   // (32,8)
#pragma unroll
  for (int r = 0; r < 4; r++)
    t[ty + r*8][tx] = p2[((size_t)b*256 + c0 + ty + r*8) * SS + s0 + tx];
  __syncthreads();
#pragma unroll
  for (int r = 0; r < 4; r++)
    p2t[((size_t)b*SS + s0 + ty + r*8) * 256 + c0 + tx] = t[tx][ty + r*8];
}

// points1 [B][256][N] fp32 -> xcat[p][0:256] bf16  (row stride 512)
__global__ void k_p1t(const float* __restrict__ p1, unsigned short* __restrict__ xcat)
{
  __shared__ float t[32][33];
  const int b = blockIdx.z, c0 = blockIdx.y * 32, n0 = blockIdx.x * 32;
  const int tx = threadIdx.x, ty = threadIdx.y;
#pragma unroll
  for (int r = 0; r < 4; r++)
    t[ty + r*8][tx] = p1[((size_t)b*256 + c0 + ty + r*8) * (size_t)NN_ + n0 + tx];
  __syncthreads();
#pragma unroll
  for (int r = 0; r < 4; r++)
    xcat[((size_t)b*NN_ + n0 + ty + r*8) * 512 + c0 + tx] = f2bf(t[tx][ty + r*8]);
}

// ---------------------------------------------------------------------------
// 3-NN + inverse-distance interp -> xcat[p][256:512] bf16
// R3: fp32 branchless top-4 scan (direct-difference, err ~1e-7*d) + fp64
// refine of the 4 candidates. fp64 top-3 is inside fp32 top-4 unless a
// rank-4/5 gap < 1e-7*d occurs (~1e-2 expected flips over all 131072 pts).
// R2's full-fp64 loop was latency-bound: 2x ds_read_b128 + fp64 chain,
// VALUBusy 45%, 189 us.
__global__ __launch_bounds__(256) void k_nn(const float* __restrict__ xyz1,
                                            const float* __restrict__ xyz2,
                                            const float* __restrict__ p2t,
                                            unsigned short* __restrict__ xcat)
{
  __shared__ float4 pts[SS];          // 16 KB, wave-uniform (broadcast) reads
  __shared__ int   ids[256][3];
  __shared__ float wts[256][3];
  const int b = blockIdx.y, n0 = blockIdx.x * 256, tid = threadIdx.x;

  for (int s = tid; s < SS; s += 256) {
    float x = xyz2[((size_t)b*3 + 0) * SS + s];
    float y = xyz2[((size_t)b*3 + 1) * SS + s];
    float z = xyz2[((size_t)b*3 + 2) * SS + s];
    pts[s] = make_float4(x, y, z, 0.0f);
  }
  __syncthreads();

  const int n = n0 + tid;
  const float qx = xyz1[((size_t)b*3 + 0) * NN_ + n];
  const float qy = xyz1[((size_t)b*3 + 1) * NN_ + n];
  const float qz = xyz1[((size_t)b*3 + 2) * NN_ + n];

  float d0 = 3.4e38f, d1 = 3.4e38f, d2 = 3.4e38f, d3 = 3.4e38f;
  int   i0 = 0, i1 = 0, i2 = 0, i3 = 0;
#pragma unroll 4
  for (int s = 0; s < SS; s++) {
    float4 p = pts[s];
    float dx = qx - p.x, dy = qy - p.y, dz = qz - p.z;
    float d = fmaf(dx, dx, fmaf(dy, dy, dz * dz));
    // branchless ordered insert into (d0<=d1<=d2<=d3); strict < keeps earlier s on ties
    bool c0 = d < d0, c1 = d < d1, c2 = d < d2, c3 = d < d3;
    d3 = c2 ? d2 : (c3 ? d : d3);  i3 = c2 ? i2 : (c3 ? s : i3);
    d2 = c1 ? d1 : (c2 ? d : d2);  i2 = c1 ? i1 : (c2 ? s : i2);
    d1 = c0 ? d0 : (c1 ? d : d1);  i1 = c0 ? i0 : (c1 ? s : i1);
    d0 = c0 ? d  : d0;             i0 = c0 ? s : i0;
  }

  // fp64 refine: recompute the 4 candidate distances exactly (inputs are fp32
  // -> fp64 conversion exact; direct-difference in fp64 matches numpy to ~1e-16)
  const double qxd = (double)qx, qyd = (double)qy, qzd = (double)qz;
  int    ii[4] = { i0, i1, i2, i3 };
  double dd[4];
#pragma unroll
  for (int k = 0; k < 4; k++) {
    float4 p = pts[ii[k]];
    double dx = qxd - (double)p.x, dy = qyd - (double)p.y, dz = qzd - (double)p.z;
    dd[k] = dx*dx + dy*dy + dz*dz;
  }
  // stable insertion sort of 4 (ties keep fp32 order; exact fp64 ties ~impossible)
#pragma unroll
  for (int a = 1; a < 4; a++)
#pragma unroll
    for (int c = a; c > 0; c--)
      if (dd[c] < dd[c-1]) {
        double td = dd[c]; dd[c] = dd[c-1]; dd[c-1] = td;
        int    ti = ii[c]; ii[c] = ii[c-1]; ii[c-1] = ti;
      }

  double r0 = 1.0/(dd[0] + 1e-8), r1 = 1.0/(dd[1] + 1e-8), r2 = 1.0/(dd[2] + 1e-8);
  double rs = 1.0/(r0 + r1 + r2);
  ids[tid][0] = ii[0]; ids[tid][1] = ii[1]; ids[tid][2] = ii[2];
  wts[tid][0] = (float)(r0*rs); wts[tid][1] = (float)(r1*rs); wts[tid][2] = (float)(r2*rs);
  __syncthreads();

  // cooperative gather: per point j, 256 threads cover 256 channels (coalesced rows)
  for (int j = 0; j < 256; j++) {
    const float* ra = p2t + ((size_t)b*SS + ids[j][0]) * 256;
    const float* rb = p2t + ((size_t)b*SS + ids[j][1]) * 256;
    const float* rc = p2t + ((size_t)b*SS + ids[j][2]) * 256;
    float f = wts[j][0]*ra[tid] + wts[j][1]*rb[tid] + wts[j][2]*rc[tid];
    xcat[((size_t)b*NN_ + n0 + j) * 512 + 256 + tid] = f2bf(f);
  }
}

// ---------------------------------------------------------------------------
// NT GEMM: Y[p][o] = sum_c X[p][c]*W[o][c].  X:[P][K] bf16, W:[256][K] bf16.
// 128x128 tile, BK=32, 4 waves (2p x 2o), MFMA 16x16x32 bf16.
// Epilogue: per-channel sum/sumsq atomics (BN stats) + bf16 store.
__global__ __launch_bounds__(256) void k_gemm(const unsigned short* __restrict__ X,
                                              const unsigned short* __restrict__ W,
                                              unsigned short* __restrict__ Y,
                                              float* __restrict__ bnsum,
                                              float* __restrict__ bnsumsq,
                                              int K)
{
  __shared__ unsigned short Xs[128*32];   // 8 KB, [p][c] rows of 64B (granule=16B)
  __shared__ unsigned short Ws[128*32];
  const int tid  = threadIdx.x;
  const int wid  = tid >> 6, lane = tid & 63;
  const int quad = lane >> 4, l16 = lane & 15;
  const int wave_p = wid & 1, wave_o = wid >> 1;
  const size_t p0 = (size_t)blockIdx.x * 128;
  const int o0 = blockIdx.y * 128;

  f32x4 acc[4][4] = {};

  // staging granule -> (row, c8): row = g>>2, coff = (g&3)*8
  const int g2 = tid + 256;
  const int r1 = tid >> 2, c1 = (tid & 3) * 8;
  const int r2 = g2 >> 2,  c2 = (g2 & 3) * 8;
  unsigned short* ldsX1 = Xs + wid*512;        unsigned short* ldsX2 = Xs + 2048 + wid*512;
  unsigned short* ldsW1 = Ws + wid*512;        unsigned short* ldsW2 = Ws + 2048 + wid*512;
  const unsigned short* gX1 = X + (p0 + r1) * (size_t)K + c1;
  const unsigned short* gX2 = X + (p0 + r2) * (size_t)K + c2;
  const unsigned short* gW1 = W + (size_t)(o0 + r1) * K + c1;
  const unsigned short* gW2 = W + (size_t)(o0 + r2) * K + c2;

  for (int kk = 0; kk < K; kk += 32) {
    async_ld16(gX1 + kk, ldsX1);
    async_ld16(gX2 + kk, ldsX2);
    async_ld16(gW1 + kk, ldsW1);
    async_ld16(gW2 + kk, ldsW2);
    __syncthreads();   // waits vmcnt(0) for the LDS-direct loads
    bf16x8 af[4], bfr[4];
    const bf16x8* xv = (const bf16x8*)Xs;
    const bf16x8* wv = (const bf16x8*)Ws;
#pragma unroll
    for (int i = 0; i < 4; i++) {
      af[i]  = xv[(wave_p*64 + i*16 + l16) * 4 + quad];  // A[m=l16][k=quad*8+j]
      bfr[i] = wv[(wave_o*64 + i*16 + l16) * 4 + quad];  // B[n=l16][k=quad*8+j]
    }
#pragma unroll
    for (int pi = 0; pi < 4; pi++)
#pragma unroll
      for (int oi = 0; oi < 4; oi++)
        acc[pi][oi] = __builtin_amdgcn_mfma_f32_16x16x32_bf16(af[pi], bfr[oi], acc[pi][oi], 0, 0, 0);
    __syncthreads();
  }

  // BN stats: reduce over p (lane's 16 rows, then across quads), atomics per o
#pragma unroll
  for (int oi = 0; oi < 4; oi++) {
    float s = 0.0f, ss = 0.0f;
#pragma unroll
    for (int pi = 0; pi < 4; pi++)
#pragma unroll
      for (int i = 0; i < 4; i++) { float v = acc[pi][oi][i]; s += v; ss += v*v; }
    s  += __shfl_xor(s, 16, 64);  s  += __shfl_xor(s, 32, 64);
    ss += __shfl_xor(ss, 16, 64); ss += __shfl_xor(ss, 32, 64);
    if (quad == 0) {
      int o = o0 + wave_o*64 + oi*16 + l16;
      atomicAdd(&bnsum[o], s);
      atomicAdd(&bnsumsq[o], ss);
    }
  }
  // store raw y (bf16). D: row(p)=quad*4+i, col(o)=l16
#pragma unroll
  for (int pi = 0; pi < 4; pi++)
#pragma unroll
    for (int oi = 0; oi < 4; oi++)
#pragma unroll
      for (int i = 0; i < 4; i++) {
        size_t p = p0 + wave_p*64 + pi*16 + quad*4 + i;
        int    o = o0 + wave_o*64 + oi*16 + l16;
        Y[p * 256 + o] = f2bf(acc[pi][oi][i]);
      }
}

// ---------------------------------------------------------------------------
// BN param: scale = g*rsqrt(var+eps), shift = be - mean*scale
__global__ void k_bn(const float* __restrict__ sum, const float* __restrict__ sumsq,
                     const float* __restrict__ g, const float* __restrict__ be,
                     float* __restrict__ scale, float* __restrict__ shift)
{
  int o = threadIdx.x;
  const float inv = 1.0f / 131072.0f;
  float m  = sum[o] * inv;
  float v  = sumsq[o] * inv - m * m;
  float sc = g[o] * rsqrtf(v + 1e-5f);
  scale[o] = sc;
  shift[o] = be[o] - m * sc;
}

// elementwise z = relu(y*scale + shift), bf16 -> bf16 (keeps GEMM2 stage-able via lds-direct)
__global__ __launch_bounds__(256) void k_z(const unsigned short* __restrict__ y,
                                           const float* __restrict__ scale,
                                           const float* __restrict__ shift,
                                           unsigned short* __restrict__ z)
{
  size_t idx = ((size_t)blockIdx.x * 256 + threadIdx.x) * 8;
  int o = (int)(idx & 255);
  u16x8 v = *(const u16x8*)(y + idx);
  u16x8 r;
#pragma unroll
  for (int i = 0; i < 8; i++) {
    float f = bf2f(v[i]);
    float t = f * scale[o + i] + shift[o + i];
    r[i] = f2bf(fmaxf(t, 0.0f));
  }
  *(u16x8*)(z + idx) = r;
}

// final: y1[p][o] bf16 -> out[b][o][n] fp32 with BN+relu, LDS transpose
__global__ __launch_bounds__(256) void k_out(const unsigned short* __restrict__ y1,
                                             const float* __restrict__ scale,
                                             const float* __restrict__ shift,
                                             float* __restrict__ out)
{
  __shared__ float t[64][65];
  const int b = blockIdx.z, o0 = blockIdx.y * 64, n0 = blockIdx.x * 64;
  const int tx = threadIdx.x & 15, ty = threadIdx.x >> 4;
  const float4 sc = *(const float4*)(scale + o0 + tx*4);
  const float4 sh = *(const float4*)(shift + o0 + tx*4);
#pragma unroll
  for (int r = 0; r < 4; r++) {
    int nl = ty + r*16;
    const unsigned short* src = y1 + ((size_t)b*NN_ + n0 + nl) * 256 + o0 + tx*4;
    ushort4 v = *(const ushort4*)src;
    t[tx*4+0][nl] = fmaxf(bf2f(v.x) * sc.x + sh.x, 0.0f);
    t[tx*4+1][nl] = fmaxf(bf2f(v.y) * sc.y + sh.y, 0.0f);
    t[tx*4+2][nl] = fmaxf(bf2f(v.z) * sc.z + sh.z, 0.0f);
    t[tx*4+3][nl] = fmaxf(bf2f(v.w) * sc.w + sh.w, 0.0f);
  }
  __syncthreads();
#pragma unroll
  for (int r = 0; r < 4; r++) {
    int ol = ty + r*16;
    float4 o4 = make_float4(t[ol][tx*4+0], t[ol][tx*4+1], t[ol][tx*4+2], t[ol][tx*4+3]);
    *(float4*)(out + ((size_t)b*256 + o0 + ol) * (size_t)NN_ + n0 + tx*4) = o4;
  }
}

// ---------------------------------------------------------------------------
extern "C" void kernel_launch(void* const* d_in, const int* in_sizes, int n_in,
                              void* d_out, int out_size, void* d_ws, size_t ws_size,
                              hipStream_t stream)
{
  const float* xyz1 = (const float*)d_in[0];
  const float* xyz2 = (const float*)d_in[1];
  const float* p1   = (const float*)d_in[2];
  const float* p2   = (const float*)d_in[3];
  const float* w0   = (const float*)d_in[4];
  const float* g0   = (const float*)d_in[6];
  const float* be0  = (const float*)d_in[7];
  const float* w1   = (const float*)d_in[8];
  const float* g1   = (const float*)d_in[10];
  const float* be1  = (const float*)d_in[11];

  // workspace layout (~192.5 MiB):
  //   [0,128Mi)    xcat [P][512] bf16      (later reused: z=[0,64Mi), y1=[64Mi,128Mi))
  //   [128,192Mi)  y0 [P][256] bf16        (p2t aliases its first 8 MiB; dead before gemm1 writes)
  //   [192Mi,...]  w0b, w1b, bn stats/params
  char* ws = (char*)d_ws;
  unsigned short* xcat = (unsigned short*)(ws);
  unsigned short* y0   = (unsigned short*)(ws + 134217728ull);
  unsigned short* zbuf = (unsigned short*)(ws);
  unsigned short* y1   = (unsigned short*)(ws + 67108864ull);
  float*          p2t  = (float*)        (ws + 134217728ull);
  unsigned short* w0b  = (unsigned short*)(ws + 201326592ull);
  unsigned short* w1b  = (unsigned short*)(ws + 201588736ull);
  float*          bn   = (float*)        (ws + 201719808ull);
  // bn: [0]sum0 [256]sumsq0 [512]sum1 [768]sumsq1 [1024]scale0 [1280]shift0 [1536]scale1 [1792]shift1

  k_prep<<<512, 256, 0, stream>>>(w0, w1, w0b, w1b, bn);
  k_p2t <<<dim3(32, 8, 8),  dim3(32, 8), 0, stream>>>(p2, p2t);
  k_p1t <<<dim3(512, 8, 8), dim3(32, 8), 0, stream>>>(p1, xcat);
  k_nn  <<<dim3(64, 8), 256, 0, stream>>>(xyz1, xyz2, p2t, xcat);
  k_gemm<<<dim3(1024, 2), 256, 0, stream>>>(xcat, w0b, y0, bn + 0,   bn + 256, 512);
  k_bn  <<<1, 256, 0, stream>>>(bn + 0,   bn + 256, g0, be0, bn + 1024, bn + 1280);
  k_z   <<<16384, 256, 0, stream>>>(y0, bn + 1024, bn + 1280, zbuf);
  k_gemm<<<dim3(1024, 2), 256, 0, stream>>>(zbuf, w1b, y1, bn + 512, bn + 768, 256);
  k_bn  <<<1, 256, 0, stream>>>(bn + 512, bn + 768, g1, be1, bn + 1536, bn + 1792);
  k_out <<<dim3(256, 4, 8), 256, 0, stream>>>(y1, bn + 1536, bn + 1792, (float*)d_out);
}

// Round 4
// 614.046 us; speedup vs baseline: 1.1564x; 1.1052x over previous
//
#include <hip/hip_runtime.h>
#include <stdint.h>

// Problem constants
#define BB    8
#define NN_   16384
#define SS    1024
#define PP    131072    // BB*NN_
#define CIN   512
#define CMID  256
#define COUT  256

typedef short  bf16x8 __attribute__((ext_vector_type(8)));
typedef float  f32x4  __attribute__((ext_vector_type(4)));
typedef unsigned short u16x8 __attribute__((ext_vector_type(8)));
typedef unsigned int uint_;

__device__ __forceinline__ float bf2f(unsigned short u){
  union { unsigned int i; float f; } v; v.i = ((unsigned int)u) << 16; return v.f;
}
__device__ __forceinline__ unsigned short f2bf(float f){
  union { float f; unsigned int i; } v; v.f = f;
  unsigned int r = (v.i + 0x7fffu + ((v.i >> 16) & 1u)) >> 16;  // RNE
  return (unsigned short)r;
}

// async global->LDS, 16B per lane; LDS dest must be wave-uniform base (+lane*16 implicit)
__device__ __forceinline__ void async_ld16(const void* g, void* l){
  const uint32_t __attribute__((address_space(1)))* gp =
    reinterpret_cast<const uint32_t __attribute__((address_space(1)))*>(reinterpret_cast<uintptr_t>(g));
  uint32_t __attribute__((address_space(3)))* lp =
    reinterpret_cast<uint32_t __attribute__((address_space(3)))*>(reinterpret_cast<uintptr_t>(l));
  __builtin_amdgcn_global_load_lds(gp, lp, 16, 0, 0);
}

// ---------------------------------------------------------------------------
// Prep: weights fp32->bf16, zero BN stats. (conv biases b0/b1 cancel exactly in
// training-mode BN: (y+b) - mean(y+b) == y - mean(y); variance unchanged.)
__global__ void k_prep(const float* __restrict__ w0, const float* __restrict__ w1,
                       unsigned short* __restrict__ w0b, unsigned short* __restrict__ w1b,
                       float* __restrict__ bn)
{
  int idx = blockIdx.x * 256 + threadIdx.x;   // grid 512 -> 131072 threads
  if (idx < 131072) w0b[idx] = f2bf(w0[idx]);
  if (idx < 65536)  w1b[idx] = f2bf(w1[idx]);
  if (idx < 2048)   bn[idx]  = 0.0f;          // stats + params region
}

// ---------------------------------------------------------------------------
// points2 [B][256][S] fp32 -> p2t [B][S][256] fp32 (coalesced gather rows)
__global__ void k_p2t(const float* __restrict__ p2, float* __restrict__ p2t)
{
  __shared__ float t[32][33];
  const int b = blockIdx.z, c0 = blockIdx.y * 32, s0 = blockIdx.x * 32;
  const int tx = threadIdx.x, ty = threadIdx.y;   // (32,8)
#pragma unroll
  for (int r = 0; r < 4; r++)
    t[ty + r*8][tx] = p2[((size_t)b*256 + c0 + ty + r*8) * SS + s0 + tx];
  __syncthreads();
#pragma unroll
  for (int r = 0; r < 4; r++)
    p2t[((size_t)b*SS + s0 + ty + r*8) * 256 + c0 + tx] = t[tx][ty + r*8];
}

// points1 [B][256][N] fp32 -> xcat[p][0:256] bf16  (row stride 512)
__global__ void k_p1t(const float* __restrict__ p1, unsigned short* __restrict__ xcat)
{
  __shared__ float t[32][33];
  const int b = blockIdx.z, c0 = blockIdx.y * 32, n0 = blockIdx.x * 32;
  const int tx = threadIdx.x, ty = threadIdx.y;
#pragma unroll
  for (int r = 0; r < 4; r++)
    t[ty + r*8][tx] = p1[((size_t)b*256 + c0 + ty + r*8) * (size_t)NN_ + n0 + tx];
  __syncthreads();
#pragma unroll
  for (int r = 0; r < 4; r++)
    xcat[((size_t)b*NN_ + n0 + ty + r*8) * 512 + c0 + tx] = f2bf(t[tx][ty + r*8]);
}

// ---------------------------------------------------------------------------
// 3-NN + inverse-distance interp -> xcat[p][256:512] bf16
// R4: (a) scan = branchless top-6 min/max network on packed u32 keys
//     (key = fp32-dist bits with low 10 bits replaced by index s; positive
//     fp32 compares as uint; ties -> smaller s, matching top_k stability).
//     No VCC round-trips (R3's cmp+cndmask chain was ~2x the issue cost).
//     fp64 refine of the 6 candidates restores exact numpy top-3 (failure
//     needs 4 points within ~0.2% rel of d3: P ~ 2e-8/query).
// (b) gather = wave-owns-64-points, float4 (16B/lane) row loads, dwordx2
//     bf16 stores, metadata via 2x ds_read_b128 broadcast.
// (c) XCD swizzle b = blk&7: all blocks of batch b share an XCD -> p2t slice
//     (1 MB) is L2-resident (R3 FETCH was 94 MB vs ~10 MB ideal).
__global__ __launch_bounds__(256) void k_nn(const float* __restrict__ xyz1,
                                            const float* __restrict__ xyz2,
                                            const float* __restrict__ p2t,
                                            unsigned short* __restrict__ xcat)
{
  __shared__ float4 pts[SS];       // 16 KB, broadcast reads
  __shared__ int4   mi[256];       // 4 KB: i0,i1,i2,pad per point
  __shared__ float4 mw[256];       // 4 KB: w0,w1,w2,pad per point
  const int blk = blockIdx.x;                  // 512 blocks
  const int b = blk & 7, nt = blk >> 3;        // XCD-aware: b == XCD id
  const int n0 = nt * 256, tid = threadIdx.x;

  for (int s = tid; s < SS; s += 256) {
    float x = xyz2[((size_t)b*3 + 0) * SS + s];
    float y = xyz2[((size_t)b*3 + 1) * SS + s];
    float z = xyz2[((size_t)b*3 + 2) * SS + s];
    pts[s] = make_float4(x, y, z, 0.0f);
  }
  __syncthreads();

  const int n = n0 + tid;
  const float qx = xyz1[((size_t)b*3 + 0) * NN_ + n];
  const float qy = xyz1[((size_t)b*3 + 1) * NN_ + n];
  const float qz = xyz1[((size_t)b*3 + 2) * NN_ + n];

  uint_ k0 = 0xFFFFFFFFu, k1 = 0xFFFFFFFFu, k2 = 0xFFFFFFFFu;
  uint_ k3 = 0xFFFFFFFFu, k4 = 0xFFFFFFFFu, k5 = 0xFFFFFFFFu;
#pragma unroll 4
  for (int s = 0; s < SS; s++) {
    float4 p = pts[s];
    float dx = qx - p.x, dy = qy - p.y, dz = qz - p.z;
    float d = fmaf(dx, dx, fmaf(dy, dy, dz * dz));
    uint_ key = (__float_as_uint(d) & 0xFFFFFC00u) | (uint_)s;
    // sorted-insert into ascending (k0..k5): new_ki = min(ki, max(k_{i-1}, key))
    // all from OLD values -> depth 2, fully parallel min/max, no vcc.
    uint_ m1 = max(k0, key);
    uint_ m2 = max(k1, key);
    uint_ m3 = max(k2, key);
    uint_ m4 = max(k3, key);
    uint_ m5 = max(k4, key);
    k0 = min(k0, key);
    k1 = min(k1, m1);
    k2 = min(k2, m2);
    k3 = min(k3, m3);
    k4 = min(k4, m4);
    k5 = min(k5, m5);
  }

  // fp64 refine: exact distances for the 6 candidates, stable sort, top-3
  const double qxd = (double)qx, qyd = (double)qy, qzd = (double)qz;
  uint_  ks[6] = { k0, k1, k2, k3, k4, k5 };
  int    ii[6];
  double dd[6];
#pragma unroll
  for (int t = 0; t < 6; t++) {
    ii[t] = (int)(ks[t] & 1023u);
    float4 p = pts[ii[t]];
    double dx = qxd - (double)p.x, dy = qyd - (double)p.y, dz = qzd - (double)p.z;
    dd[t] = dx*dx + dy*dy + dz*dz;
  }
#pragma unroll
  for (int a = 1; a < 6; a++)
#pragma unroll
    for (int c = a; c > 0; c--)
      if (dd[c] < dd[c-1]) {
        double td = dd[c]; dd[c] = dd[c-1]; dd[c-1] = td;
        int    ti = ii[c]; ii[c] = ii[c-1]; ii[c-1] = ti;
      }

  double r0 = 1.0/(dd[0] + 1e-8), r1 = 1.0/(dd[1] + 1e-8), r2 = 1.0/(dd[2] + 1e-8);
  double rs = 1.0/(r0 + r1 + r2);
  mi[tid] = make_int4(ii[0], ii[1], ii[2], 0);
  mw[tid] = make_float4((float)(r0*rs), (float)(r1*rs), (float)(r2*rs), 0.0f);
  __syncthreads();

  // gather: wave w interpolates points j in [w*64, w*64+64); lane covers 4 ch
  const int wid = tid >> 6, lane = tid & 63;
  const float* p2tb = p2t + (size_t)b * SS * 256;
  unsigned short* outb = xcat + ((size_t)b*NN_ + n0) * 512 + 256 + lane*4;
#pragma unroll 2
  for (int t = 0; t < 64; t++) {
    int j = wid*64 + t;
    int4   im = mi[j];                 // broadcast ds_read_b128
    float4 wm = mw[j];
    const float4* ra = (const float4*)(p2tb + (size_t)im.x * 256) + lane;
    const float4* rb = (const float4*)(p2tb + (size_t)im.y * 256) + lane;
    const float4* rc = (const float4*)(p2tb + (size_t)im.z * 256) + lane;
    float4 A = *ra, Bv = *rb, Cv = *rc;
    float fx = wm.x*A.x + wm.y*Bv.x + wm.z*Cv.x;
    float fy = wm.x*A.y + wm.y*Bv.y + wm.z*Cv.y;
    float fz = wm.x*A.z + wm.y*Bv.z + wm.z*Cv.z;
    float fw = wm.x*A.w + wm.y*Bv.w + wm.z*Cv.w;
    uint_ lo = (uint_)f2bf(fx) | ((uint_)f2bf(fy) << 16);
    uint_ hi = (uint_)f2bf(fz) | ((uint_)f2bf(fw) << 16);
    uint2 pk; pk.x = lo; pk.y = hi;
    *(uint2*)(outb + (size_t)j * 512) = pk;
  }
}

// ---------------------------------------------------------------------------
// NT GEMM: Y[p][o] = sum_c X[p][c]*W[o][c].  X:[P][K] bf16, W:[256][K] bf16.
// 128x128 tile, BK=32, 4 waves (2p x 2o), MFMA 16x16x32 bf16.
// Epilogue: per-channel sum/sumsq atomics (BN stats) + bf16 store.
__global__ __launch_bounds__(256) void k_gemm(const unsigned short* __restrict__ X,
                                              const unsigned short* __restrict__ W,
                                              unsigned short* __restrict__ Y,
                                              float* __restrict__ bnsum,
                                              float* __restrict__ bnsumsq,
                                              int K)
{
  __shared__ unsigned short Xs[128*32];   // 8 KB, [p][c] rows of 64B (granule=16B)
  __shared__ unsigned short Ws[128*32];
  const int tid  = threadIdx.x;
  const int wid  = tid >> 6, lane = tid & 63;
  const int quad = lane >> 4, l16 = lane & 15;
  const int wave_p = wid & 1, wave_o = wid >> 1;
  const size_t p0 = (size_t)blockIdx.x * 128;
  const int o0 = blockIdx.y * 128;

  f32x4 acc[4][4] = {};

  // staging granule -> (row, c8): row = g>>2, coff = (g&3)*8
  const int g2 = tid + 256;
  const int r1 = tid >> 2, c1 = (tid & 3) * 8;
  const int r2 = g2 >> 2,  c2 = (g2 & 3) * 8;
  unsigned short* ldsX1 = Xs + wid*512;        unsigned short* ldsX2 = Xs + 2048 + wid*512;
  unsigned short* ldsW1 = Ws + wid*512;        unsigned short* ldsW2 = Ws + 2048 + wid*512;
  const unsigned short* gX1 = X + (p0 + r1) * (size_t)K + c1;
  const unsigned short* gX2 = X + (p0 + r2) * (size_t)K + c2;
  const unsigned short* gW1 = W + (size_t)(o0 + r1) * K + c1;
  const unsigned short* gW2 = W + (size_t)(o0 + r2) * K + c2;

  for (int kk = 0; kk < K; kk += 32) {
    async_ld16(gX1 + kk, ldsX1);
    async_ld16(gX2 + kk, ldsX2);
    async_ld16(gW1 + kk, ldsW1);
    async_ld16(gW2 + kk, ldsW2);
    __syncthreads();   // waits vmcnt(0) for the LDS-direct loads
    bf16x8 af[4], bfr[4];
    const bf16x8* xv = (const bf16x8*)Xs;
    const bf16x8* wv = (const bf16x8*)Ws;
#pragma unroll
    for (int i = 0; i < 4; i++) {
      af[i]  = xv[(wave_p*64 + i*16 + l16) * 4 + quad];  // A[m=l16][k=quad*8+j]
      bfr[i] = wv[(wave_o*64 + i*16 + l16) * 4 + quad];  // B[n=l16][k=quad*8+j]
    }
#pragma unroll
    for (int pi = 0; pi < 4; pi++)
#pragma unroll
      for (int oi = 0; oi < 4; oi++)
        acc[pi][oi] = __builtin_amdgcn_mfma_f32_16x16x32_bf16(af[pi], bfr[oi], acc[pi][oi], 0, 0, 0);
    __syncthreads();
  }

  // BN stats: reduce over p (lane's 16 rows, then across quads), atomics per o
#pragma unroll
  for (int oi = 0; oi < 4; oi++) {
    float s = 0.0f, ss = 0.0f;
#pragma unroll
    for (int pi = 0; pi < 4; pi++)
#pragma unroll
      for (int i = 0; i < 4; i++) { float v = acc[pi][oi][i]; s += v; ss += v*v; }
    s  += __shfl_xor(s, 16, 64);  s  += __shfl_xor(s, 32, 64);
    ss += __shfl_xor(ss, 16, 64); ss += __shfl_xor(ss, 32, 64);
    if (quad == 0) {
      int o = o0 + wave_o*64 + oi*16 + l16;
      atomicAdd(&bnsum[o], s);
      atomicAdd(&bnsumsq[o], ss);
    }
  }
  // store raw y (bf16). D: row(p)=quad*4+i, col(o)=l16
#pragma unroll
  for (int pi = 0; pi < 4; pi++)
#pragma unroll
    for (int oi = 0; oi < 4; oi++)
#pragma unroll
      for (int i = 0; i < 4; i++) {
        size_t p = p0 + wave_p*64 + pi*16 + quad*4 + i;
        int    o = o0 + wave_o*64 + oi*16 + l16;
        Y[p * 256 + o] = f2bf(acc[pi][oi][i]);
      }
}

// ---------------------------------------------------------------------------
// BN param: scale = g*rsqrt(var+eps), shift = be - mean*scale
__global__ void k_bn(const float* __restrict__ sum, const float* __restrict__ sumsq,
                     const float* __restrict__ g, const float* __restrict__ be,
                     float* __restrict__ scale, float* __restrict__ shift)
{
  int o = threadIdx.x;
  const float inv = 1.0f / 131072.0f;
  float m  = sum[o] * inv;
  float v  = sumsq[o] * inv - m * m;
  float sc = g[o] * rsqrtf(v + 1e-5f);
  scale[o] = sc;
  shift[o] = be[o] - m * sc;
}

// elementwise z = relu(y*scale + shift), bf16 -> bf16 (keeps GEMM2 stage-able via lds-direct)
__global__ __launch_bounds__(256) void k_z(const unsigned short* __restrict__ y,
                                           const float* __restrict__ scale,
                                           const float* __restrict__ shift,
                                           unsigned short* __restrict__ z)
{
  size_t idx = ((size_t)blockIdx.x * 256 + threadIdx.x) * 8;
  int o = (int)(idx & 255);
  u16x8 v = *(const u16x8*)(y + idx);
  u16x8 r;
#pragma unroll
  for (int i = 0; i < 8; i++) {
    float f = bf2f(v[i]);
    float t = f * scale[o + i] + shift[o + i];
    r[i] = f2bf(fmaxf(t, 0.0f));
  }
  *(u16x8*)(z + idx) = r;
}

// final: y1[p][o] bf16 -> out[b][o][n] fp32 with BN+relu, LDS transpose
__global__ __launch_bounds__(256) void k_out(const unsigned short* __restrict__ y1,
                                             const float* __restrict__ scale,
                                             const float* __restrict__ shift,
                                             float* __restrict__ out)
{
  __shared__ float t[64][65];
  const int b = blockIdx.z, o0 = blockIdx.y * 64, n0 = blockIdx.x * 64;
  const int tx = threadIdx.x & 15, ty = threadIdx.x >> 4;
  const float4 sc = *(const float4*)(scale + o0 + tx*4);
  const float4 sh = *(const float4*)(shift + o0 + tx*4);
#pragma unroll
  for (int r = 0; r < 4; r++) {
    int nl = ty + r*16;
    const unsigned short* src = y1 + ((size_t)b*NN_ + n0 + nl) * 256 + o0 + tx*4;
    ushort4 v = *(const ushort4*)src;
    t[tx*4+0][nl] = fmaxf(bf2f(v.x) * sc.x + sh.x, 0.0f);
    t[tx*4+1][nl] = fmaxf(bf2f(v.y) * sc.y + sh.y, 0.0f);
    t[tx*4+2][nl] = fmaxf(bf2f(v.z) * sc.z + sh.z, 0.0f);
    t[tx*4+3][nl] = fmaxf(bf2f(v.w) * sc.w + sh.w, 0.0f);
  }
  __syncthreads();
#pragma unroll
  for (int r = 0; r < 4; r++) {
    int ol = ty + r*16;
    float4 o4 = make_float4(t[ol][tx*4+0], t[ol][tx*4+1], t[ol][tx*4+2], t[ol][tx*4+3]);
    *(float4*)(out + ((size_t)b*256 + o0 + ol) * (size_t)NN_ + n0 + tx*4) = o4;
  }
}

// ---------------------------------------------------------------------------
extern "C" void kernel_launch(void* const* d_in, const int* in_sizes, int n_in,
                              void* d_out, int out_size, void* d_ws, size_t ws_size,
                              hipStream_t stream)
{
  const float* xyz1 = (const float*)d_in[0];
  const float* xyz2 = (const float*)d_in[1];
  const float* p1   = (const float*)d_in[2];
  const float* p2   = (const float*)d_in[3];
  const float* w0   = (const float*)d_in[4];
  const float* g0   = (const float*)d_in[6];
  const float* be0  = (const float*)d_in[7];
  const float* w1   = (const float*)d_in[8];
  const float* g1   = (const float*)d_in[10];
  const float* be1  = (const float*)d_in[11];

  // workspace layout (~192.5 MiB):
  //   [0,128Mi)    xcat [P][512] bf16      (later reused: z=[0,64Mi), y1=[64Mi,128Mi))
  //   [128,192Mi)  y0 [P][256] bf16        (p2t aliases its first 8 MiB; dead before gemm1 writes)
  //   [192Mi,...]  w0b, w1b, bn stats/params
  char* ws = (char*)d_ws;
  unsigned short* xcat = (unsigned short*)(ws);
  unsigned short* y0   = (unsigned short*)(ws + 134217728ull);
  unsigned short* zbuf = (unsigned short*)(ws);
  unsigned short* y1   = (unsigned short*)(ws + 67108864ull);
  float*          p2t  = (float*)        (ws + 134217728ull);
  unsigned short* w0b  = (unsigned short*)(ws + 201326592ull);
  unsigned short* w1b  = (unsigned short*)(ws + 201588736ull);
  float*          bn   = (float*)        (ws + 201719808ull);
  // bn: [0]sum0 [256]sumsq0 [512]sum1 [768]sumsq1 [1024]scale0 [1280]shift0 [1536]scale1 [1792]shift1

  k_prep<<<512, 256, 0, stream>>>(w0, w1, w0b, w1b, bn);
  k_p2t <<<dim3(32, 8, 8),  dim3(32, 8), 0, stream>>>(p2, p2t);
  k_p1t <<<dim3(512, 8, 8), dim3(32, 8), 0, stream>>>(p1, xcat);
  k_nn  <<<512, 256, 0, stream>>>(xyz1, xyz2, p2t, xcat);
  k_gemm<<<dim3(1024, 2), 256, 0, stream>>>(xcat, w0b, y0, bn + 0,   bn + 256, 512);
  k_bn  <<<1, 256, 0, stream>>>(bn + 0,   bn + 256, g0, be0, bn + 1024, bn + 1280);
  k_z   <<<16384, 256, 0, stream>>>(y0, bn + 1024, bn + 1280, zbuf);
  k_gemm<<<dim3(1024, 2), 256, 0, stream>>>(zbuf, w1b, y1, bn + 512, bn + 768, 256);
  k_bn  <<<1, 256, 0, stream>>>(bn + 512, bn + 768, g1, be1, bn + 1536, bn + 1792);
  k_out <<<dim3(256, 4, 8), 256, 0, stream>>>(y1, bn + 1536, bn + 1792, (float*)d_out);
}